// Round 1
// 925.056 us; speedup vs baseline: 1.5187x; 1.5187x over previous
//
#include <hip/hip_runtime.h>
#include <cstddef>
#include <cstdint>

// B=64, T_CAP=32, V=32000, E=D=1024, gates=4096, t_dec=31.
// d_out: preds[64*31*32000] ++ decode_lengths[64] ++ sort_ind[64]  (float dtype detected at runtime).
// Runtime dtype dispatch: flags[0]=1 if floats are fp32 (else bf16), flags[1]=1 if ints are int64.
// Scratch layout in d_out's preds region (dead until k_gemm_fc overwrites it; region >= 121MB):
//   gatesx fp32 [0,32MB) ++ Xbuf bf16 [32,36MB) ++ Whh16 bf16 [36,44.4MB) ++ Wih16 bf16 [44.4,52.8MB)
// d_ws: flags+wsI+Cbuf+Hbuf (~4.5MB) ++ (optional, if ws_size>=74MB) fcW16 bf16 @ +8MB (65.5MB).
#define PRED_N 63488000

typedef unsigned short u16;
typedef unsigned long long u64;
typedef __attribute__((ext_vector_type(8))) unsigned short us8;
typedef __attribute__((ext_vector_type(4))) float f32x4;
typedef __attribute__((ext_vector_type(8))) __bf16 bf16x8;

__device__ __forceinline__ float bf2f(u16 h){
  unsigned u = ((unsigned)h) << 16;
  return __builtin_bit_cast(float, u);
}
__device__ __forceinline__ u16 f2bf(float f){
  unsigned u = __builtin_bit_cast(unsigned, f);
  u += 0x7FFFu + ((u >> 16) & 1u);
  return (u16)(u >> 16);
}
__device__ __forceinline__ float sigf(float x){ return 1.f/(1.f + __expf(-x)); }
__device__ __forceinline__ float tanhf_(float x){ return 1.f - 2.f/(__expf(2.f*x) + 1.f); }

__device__ __forceinline__ f32x4 mfma16(us8 a, us8 b, f32x4 c){
  return __builtin_amdgcn_mfma_f32_16x16x32_bf16(
      __builtin_bit_cast(bf16x8, a), __builtin_bit_cast(bf16x8, b), c, 0, 0, 0);
}
__device__ __forceinline__ u64 pack4bf(const float* h){
  return (u64)f2bf(h[0]) | ((u64)f2bf(h[1]) << 16)
       | ((u64)f2bf(h[2]) << 32) | ((u64)f2bf(h[3]) << 48);
}
__device__ __forceinline__ us8 pack8(float4 a, float4 b){
  us8 r;
  r[0]=f2bf(a.x); r[1]=f2bf(a.y); r[2]=f2bf(a.z); r[3]=f2bf(a.w);
  r[4]=f2bf(b.x); r[5]=f2bf(b.y); r[6]=f2bf(b.z); r[7]=f2bf(b.w);
  return r;
}
// scalar read of a float array of unknown dtype
__device__ __forceinline__ float ldf(const void* p, int f32, int i){
  return f32 ? ((const float*)p)[i] : bf2f(((const u16*)p)[i]);
}
__device__ __forceinline__ int ldi(const int* p, int i64, int i){
  return i64 ? p[2*i] : p[i];   // little-endian low word; values < 2^31
}

// ---------------- K0: dtype detector ----------------
__global__ void k_detect(const unsigned* __restrict__ embw, const int* __restrict__ lenw,
                         int* __restrict__ flags){
  if(threadIdx.x == 0){
    int hits = 0;
    for(int i = 0; i < 16; ++i){
      unsigned w = embw[i];
      int elo = (w >> 7) & 0xFF, ehi = (w >> 23) & 0xFF;
      hits += (elo >= 112 && elo <= 133) && (ehi >= 112 && ehi <= 133);
    }
    flags[0] = (hits >= 12) ? 0 : 1;        // 1 = fp32 floats
    int orv = 0;
    for(int i = 0; i < 4; ++i) orv |= lenw[2*i + 1];
    flags[1] = (orv == 0) ? 1 : 0;          // 1 = int64 ints (lengths>=2, so int32 odd words !=0)
  }
}

// ---------------- K1: stable descending sort + tail outputs ----------------
__global__ void k_setup(const int* __restrict__ lens, int* __restrict__ wsI,
                        const int* __restrict__ flags, void* __restrict__ out){
  const int i = threadIdx.x;                // 64 threads
  const int f32 = flags[0], i64 = flags[1];
  const int li = ldi(lens, i64, i);
  int rank = 0;
  for(int j = 0; j < 64; ++j){
    const int lj = ldi(lens, i64, j);
    rank += (lj > li) || (lj == li && j < i);   // stable descending
  }
  wsI[rank]      = i;                       // sort_ind
  wsI[64 + rank] = li - 1;                  // decode_lengths (sorted order)
  if(f32){
    ((float*)out)[PRED_N + rank]      = (float)(li - 1);
    ((float*)out)[PRED_N + 64 + rank] = (float)i;
  } else {
    ((u16*)out)[PRED_N + rank]      = f2bf((float)(li - 1));
    ((u16*)out)[PRED_N + 64 + rank] = f2bf((float)i);
  }
}

// ---------------- K1b: weight convert (fp32 -> bf16 RNE, or copy if already bf16) ----------------
__global__ void __launch_bounds__(256) k_conv16(const void* __restrict__ W,
    const int* __restrict__ flags, u16* __restrict__ dst, int n8){
  const int f32 = flags[0];
  const int stride = gridDim.x * 256;
  for(int i = blockIdx.x * 256 + threadIdx.x; i < n8; i += stride){
    if(f32){
      const float4* s = (const float4*)W + 2 * (size_t)i;
      ((us8*)dst)[i] = pack8(s[0], s[1]);
    } else {
      ((uint4*)dst)[i] = ((const uint4*)W)[i];
    }
  }
}

// ---------------- K2: build X (2048x1024 bf16), row t*64+b ----------------
__global__ void __launch_bounds__(256) k_gather(const void* __restrict__ enc,
    const int* __restrict__ caps, const void* __restrict__ emb,
    const int* __restrict__ wsI, const int* __restrict__ flags, u16* __restrict__ X){
  const int r = blockIdx.x, t = r >> 6, b = r & 63;
  const int f32 = flags[0], i64 = flags[1];
  const int sb = wsI[b];
  const size_t rowoff = (t == 0) ? (size_t)sb * 1024
                                 : (size_t)ldi(caps, i64, sb * 32 + (t - 1)) * 1024;
  const void* base = (t == 0) ? enc : emb;
  u16* dst = X + (size_t)r * 1024;
  if(f32){
    const float4* src = (const float4*)((const float*)base + rowoff);
    float4 v = src[threadIdx.x];            // 4 floats per thread
    u64 w = (u64)f2bf(v.x) | ((u64)f2bf(v.y) << 16)
          | ((u64)f2bf(v.z) << 32) | ((u64)f2bf(v.w) << 48);
    ((u64*)dst)[threadIdx.x] = w;
  } else {
    const uint2* src = (const uint2*)((const u16*)base + rowoff);
    ((uint2*)dst)[threadIdx.x] = src[threadIdx.x];  // 4 bf16 per thread
  }
}

// ---------------- 128x128 K=1024 MFMA mainloop; A always bf16, B dtype-flagged ----------------
__device__ __forceinline__ void gemm_main(const u16* __restrict__ A, const void* __restrict__ Bv,
    int bF32, int arowmax, u16* As, u16* Bs, f32x4 (&acc)[4][4]){
  const int tid = threadIdx.x, wave = tid >> 6, lane = tid & 63;
  const int mq = (wave >> 1) * 64, nq = (wave & 1) * 64;
  const int l15 = lane & 15, lq = lane >> 4;
  const int r0 = lane >> 2, c0 = (lane & 3) * 8;     // within a 16x32 chunk
  const u16* Bb = (const u16*)Bv; const float* Bf = (const float*)Bv;
  for(int k0 = 0; k0 < 1024; k0 += 32){
    us8 av[2], bv[2];
#pragma unroll
    for(int c2 = 0; c2 < 2; ++c2){
      const int chunk = wave * 2 + c2;               // 8 chunks of 16 rows
      int ar = chunk * 16 + r0; if(ar > arowmax) ar = arowmax;
      av[c2] = *(const us8*)(A + (size_t)ar * 1024 + k0 + c0);
      const size_t bo = (size_t)(chunk * 16 + r0) * 1024 + k0 + c0;
      if(bF32){
        const float* p = Bf + bo;
        bv[c2] = pack8(*(const float4*)p, *(const float4*)(p + 4));
      } else {
        bv[c2] = *(const us8*)(Bb + bo);
      }
    }
    __syncthreads();   // previous iteration's LDS reads complete
#pragma unroll
    for(int c2 = 0; c2 < 2; ++c2){
      const int chunk = wave * 2 + c2;
      *(us8*)&As[chunk * 512 + r0 * 32 + c0] = av[c2];
      *(us8*)&Bs[chunk * 512 + r0 * 32 + c0] = bv[c2];
    }
    __syncthreads();
    us8 af[4], bfv[4];
#pragma unroll
    for(int i = 0; i < 4; ++i){
      af[i]  = *(const us8*)&As[(mq + i * 16 + l15) * 32 + lq * 8];
      bfv[i] = *(const us8*)&Bs[(nq + i * 16 + l15) * 32 + lq * 8];
    }
#pragma unroll
    for(int i = 0; i < 4; ++i)
#pragma unroll
      for(int j = 0; j < 4; ++j)
        acc[i][j] = mfma16(af[i], bfv[j], acc[i][j]);
  }
}

// ---------------- K3: gates_x = X @ W_ih^T + (b_ih + b_hh), fp32; B is pre-converted bf16 ----------------
__global__ void __launch_bounds__(256) k_gemm_gates(const u16* __restrict__ X,
    const u16* __restrict__ Wih16, const void* __restrict__ bih, const void* __restrict__ bhh,
    const int* __restrict__ flags, float* __restrict__ gatesx){
  __shared__ u16 As[4096], Bs[4096];
  const int tid = threadIdx.x, wave = tid >> 6, lane = tid & 63;
  const int bm = blockIdx.x, bn = blockIdx.y;        // bm fastest: same-strip blocks adjacent
  const int mq = (wave >> 1) * 64, nq = (wave & 1) * 64;
  const int l15 = lane & 15, lq = lane >> 4;
  const int f32 = flags[0];
  f32x4 acc[4][4] = {};
  gemm_main(X + (size_t)bm * 128 * 1024, Wih16 + (size_t)bn * 128 * 1024, 0, 127, As, Bs, acc);
  const int rowb = bm * 128 + mq, colb = bn * 128 + nq;
#pragma unroll
  for(int j = 0; j < 4; ++j){
    const int col = colb + j * 16 + l15;
    const float bias = ldf(bih, f32, col) + ldf(bhh, f32, col);
#pragma unroll
    for(int i = 0; i < 4; ++i)
#pragma unroll
      for(int v = 0; v < 4; ++v){
        const int row = rowb + i * 16 + lq * 4 + v;
        gatesx[(size_t)row * 4096 + col] = acc[i][j][v] + bias;
      }
  }
}

// ---------------- K4: initial LSTM cell (h=c=0) ----------------
__global__ void __launch_bounds__(256) k_init(const float* __restrict__ gatesx,
    u16* __restrict__ Hbuf, float* __restrict__ Cbuf){
  const int m = blockIdx.x, d0 = threadIdx.x * 4;
  const float* gx = gatesx + (size_t)m * 4096 + d0;
  f32x4 iv = *(const f32x4*)(gx);
  f32x4 gv = *(const f32x4*)(gx + 2048);
  f32x4 ov = *(const f32x4*)(gx + 3072);
  f32x4 cv; float h[4];
#pragma unroll
  for(int e = 0; e < 4; ++e){
    const float cn = sigf(iv[e]) * tanhf_(gv[e]);    // f*c vanishes (c=0)
    cv[e] = cn;
    h[e] = sigf(ov[e]) * tanhf_(cn);
  }
  *(f32x4*)(Cbuf + (size_t)m * 1024 + d0) = cv;
  *(u64*)(Hbuf + (size_t)m * 1024 + d0) = pack4bf(h);
}

// ---------------- K5: one recurrent step, 256 blocks x 4 dims (launched 31x) ----------------
// Block blk owns dims [blk*4, blk*4+4) x 4 gates = one 16-wide N-tile.
// 4 waves split K=1024 into 4x256; LDS reduce; epilogue: 1 thread = 1 (m,dim).
__global__ void __launch_bounds__(256) k_step2(const u16* __restrict__ Whh16,
    const float* __restrict__ gatesx, const int* __restrict__ wsI,
    u16* __restrict__ Hbuf, float* __restrict__ Cbuf, int t){
  __shared__ float red[4096];           // 4 waves x 64m x 16n partials
  const int tid = threadIdx.x, wave = tid >> 6, lane = tid & 63, blk = blockIdx.x;
  const int l15 = lane & 15, lq = lane >> 4;
  // B-fragment row (n = l15): gate = l15>>2, dim-offset = l15&3
  const int brow = (l15 >> 2) * 1024 + blk * 4 + (l15 & 3);
  const u16* Bp = Whh16 + (size_t)brow * 1024 + wave * 256 + lq * 8;
  const u16* Ap = Hbuf + (size_t)t * 65536 + wave * 256 + lq * 8;
  f32x4 acc[4] = {};
#pragma unroll
  for(int kt = 0; kt < 8; ++kt){
    const us8 bw = *(const us8*)(Bp + kt * 32);
#pragma unroll
    for(int mi = 0; mi < 4; ++mi){
      const us8 af = *(const us8*)(Ap + (size_t)(mi * 16 + l15) * 1024 + kt * 32);
      acc[mi] = mfma16(af, bw, acc[mi]);
    }
  }
#pragma unroll
  for(int mi = 0; mi < 4; ++mi)
#pragma unroll
    for(int v = 0; v < 4; ++v)
      red[wave * 1024 + (mi * 16 + lq * 4 + v) * 16 + l15] = acc[mi][v];
  __syncthreads();

  const int m = tid >> 2, dr = tid & 3;
  const int dim = blk * 4 + dr;
  const int dlm = wsI[64 + m];
  const float* gx = gatesx + ((size_t)(t + 1) * 64 + m) * 4096 + dim;
  float g4[4];
#pragma unroll
  for(int g = 0; g < 4; ++g){
    const int n = g * 4 + dr;
    g4[g] = red[m * 16 + n] + red[1024 + m * 16 + n]
          + red[2048 + m * 16 + n] + red[3072 + m * 16 + n]
          + gx[(size_t)g * 1024];
  }
  u16* hdst = Hbuf + ((size_t)(t + 1) * 64 + m) * 1024 + dim;
  if(t < dlm){
    float* cp = Cbuf + (size_t)m * 1024 + dim;
    const float cn = sigf(g4[1]) * (*cp) + sigf(g4[0]) * tanhf_(g4[2]);
    *cp = cn;
    *hdst = f2bf(sigf(g4[3]) * tanhf_(cn));
  } else {
    *hdst = Hbuf[((size_t)t * 64 + m) * 1024 + dim];  // carry h (c untouched)
  }
}

// ---------------- K6: preds = H @ fc_W^T + fc_b, masked; XCD-chunked swizzle ----------------
__global__ void __launch_bounds__(256) k_gemm_fc(const u16* __restrict__ H,
    const void* __restrict__ fcW, const u16* __restrict__ fcW16, const int useW16,
    const void* __restrict__ fcb, const int* __restrict__ declen,
    const int* __restrict__ flags, void* __restrict__ out){
  __shared__ u16 As[4096], Bs[4096];
  const int tid = threadIdx.x, wave = tid >> 6, lane = tid & 63;
  // 4000 blocks; XCD-chunked bijective swizzle (4000%8==0): XCD x gets L in [x*500,(x+1)*500).
  // bm = L&15 innermost: the 16 blocks sharing one B-strip are <=128 dispatch slots apart -> L2-resident strip.
  const int bid = blockIdx.x;
  const int L = (bid & 7) * 500 + (bid >> 3);
  const int bm = L & 15, bn = L >> 4;
  const int mq = (wave >> 1) * 64, nq = (wave & 1) * 64;
  const int l15 = lane & 15, lq = lane >> 4;
  const int f32 = flags[0];
  const int bf32 = useW16 ? 0 : f32;
  f32x4 acc[4][4] = {};
  const int amax0 = 1983 - bm * 128;
  const void* Bbase = useW16 ? (const void*)(fcW16 + (size_t)bn * 128 * 1024)
      : (f32 ? (const void*)((const float*)fcW + (size_t)bn * 128 * 1024)
             : (const void*)((const u16*)fcW + (size_t)bn * 128 * 1024));
  gemm_main(H + (size_t)bm * 128 * 1024, Bbase, bf32,
            amax0 > 127 ? 127 : amax0, As, Bs, acc);
  const int rowb = bm * 128 + mq, colb = bn * 128 + nq;
  int   col[4];
  float bias[4];
#pragma unroll
  for(int j = 0; j < 4; ++j){
    col[j] = colb + j * 16 + l15;
    bias[j] = ldf(fcb, f32, col[j]);
  }
#pragma unroll
  for(int i = 0; i < 4; ++i)
#pragma unroll
    for(int v = 0; v < 4; ++v){
      const int row = rowb + i * 16 + lq * 4 + v;     // row = t*64 + b
      if(row < 1984){
        const int t = row >> 6, b = row & 63;
        const bool act = (t < declen[b]);
        const size_t obase = (size_t)b * 992000 + (size_t)t * 32000;
#pragma unroll
        for(int j = 0; j < 4; ++j){
          const float val = act ? (acc[i][j][v] + bias[j]) : 0.f;
          if(f32) ((float*)out)[obase + col[j]] = val;
          else    ((u16*)out)[obase + col[j]] = f2bf(val);
        }
      }
    }
}

extern "C" void kernel_launch(void* const* d_in, const int* in_sizes, int n_in,
                              void* d_out, int out_size, void* d_ws, size_t ws_size,
                              hipStream_t stream){
  const void* enc = d_in[0];
  const int*  caps = (const int*)d_in[1];
  const int*  lens = (const int*)d_in[2];
  const void* emb = d_in[3];
  const void* Wih = d_in[4];
  const void* Whh = d_in[5];
  const void* bih = d_in[6];
  const void* bhh = d_in[7];
  const void* fcW = d_in[8];
  const void* fcb = d_in[9];

  // Big scratch in d_out's preds region (dead until k_gemm_fc overwrites it):
  float* gatesx = (float*)d_out;                                   // 32 MB fp32 @ +0
  u16*   Xbuf   = (u16*)((char*)d_out + (size_t)32*1024*1024);     // 4 MB bf16 @ +32MB
  u16*   Whh16  = (u16*)((char*)d_out + (size_t)36*1024*1024);     // 8 MB bf16 @ +36MB
  u16*   Wih16  = (u16*)((char*)d_out + (size_t)36*1024*1024 + 8388608); // 8 MB bf16 @ +44.4MB
  // Small persistent scratch in d_ws (~4.5 MB):
  char* ws = (char*)d_ws;
  int*   flags = (int*)ws;                                         // [0]=fp32?, [1]=int64?
  int*   wsI   = (int*)(ws + 256);                                 // [0..63] sort_ind, [64..127] declen
  float* Cbuf  = (float*)(ws + 1024);                              // 64x1024 fp32 = 256 KB
  u16*   Hbuf  = (u16*)(ws + (size_t)512*1024);                    // 2048x1024 bf16 = 4 MB
  u16*   fcW16 = (u16*)(ws + (size_t)8*1024*1024);                 // 65.5 MB bf16 (optional)
  const int useFc16 = (ws_size >= (size_t)74*1024*1024) ? 1 : 0;

  hipLaunchKernelGGL(k_detect, dim3(1), dim3(64), 0, stream,
                     (const unsigned*)emb, lens, flags);
  hipLaunchKernelGGL(k_setup, dim3(1), dim3(64), 0, stream, lens, wsI, flags, d_out);
  hipLaunchKernelGGL(k_conv16, dim3(2048), dim3(256), 0, stream, Wih, flags, Wih16, 524288);
  hipLaunchKernelGGL(k_conv16, dim3(2048), dim3(256), 0, stream, Whh, flags, Whh16, 524288);
  if(useFc16)
    hipLaunchKernelGGL(k_conv16, dim3(4096), dim3(256), 0, stream, fcW, flags, fcW16, 4096000);
  hipLaunchKernelGGL(k_gather, dim3(2048), dim3(256), 0, stream, enc, caps, emb, wsI, flags, Xbuf);
  hipLaunchKernelGGL(k_gemm_gates, dim3(16, 32), dim3(256), 0, stream, Xbuf, Wih16, bih, bhh, flags, gatesx);
  hipLaunchKernelGGL(k_init, dim3(64), dim3(256), 0, stream, gatesx, Hbuf, Cbuf);
  for(int t = 0; t < 31; ++t)
    hipLaunchKernelGGL(k_step2, dim3(256), dim3(256), 0, stream, Whh16, gatesx, wsI, Hbuf, Cbuf, t);
  hipLaunchKernelGGL(k_gemm_fc, dim3(4000), dim3(256), 0, stream,
                     Hbuf + (size_t)64 * 1024, fcW, fcW16, useFc16, fcb, wsI + 64, flags, d_out);
}